// Round 11
// baseline (338.390 us; speedup 1.0000x reference)
//
#include <hip/hip_runtime.h>
#include <hip/hip_bf16.h>
#include <cstdint>

// SemlaLayer fused forward for MI355X (gfx950).
// R11: 16-wave (1024-thr) blocks, 1 block/CU => 4 waves/SIMD (50% occupancy)
// with R8-10's low-traffic structure. W1 16 cols/wave (24 VGPR), W2 16 cols
// on waves 0-8 (32 VGPR), GEMM2 tile 8 -> wave 8 (no double-duty wave).
// 2 barriers/tile, in-register softmax, reg-staged next tile.

typedef __bf16 bf16x4_t __attribute__((ext_vector_type(4)));
typedef __bf16 bf16x8_t __attribute__((ext_vector_type(8)));
typedef float  f32x4_t  __attribute__((ext_vector_type(4)));

#define SP 76   // sS pitch in floats
#define KV 32   // k-tile rows

__device__ __forceinline__ int swzX(int row, int col) {   // pitch 192
    return row * 192 + (col ^ ((row & 7) << 3));
}
__device__ __forceinline__ int swzH(int row, int col) {   // pitch 256
    return (row << 8) + (col ^ ((row & 7) << 3));
}

__device__ __forceinline__ bf16x8_t cvt8(f32x4_t a, f32x4_t b) {
    bf16x8_t r;
    r[0] = (__bf16)a.x; r[1] = (__bf16)a.y; r[2] = (__bf16)a.z; r[3] = (__bf16)a.w;
    r[4] = (__bf16)b.x; r[5] = (__bf16)b.y; r[6] = (__bf16)b.z; r[7] = (__bf16)b.w;
    return r;
}
__device__ __forceinline__ bf16x4_t cvt4(f32x4_t a) {
    bf16x4_t r;
    r[0] = (__bf16)a.x; r[1] = (__bf16)a.y; r[2] = (__bf16)a.z; r[3] = (__bf16)a.w;
    return r;
}

// ---------------- pre-kernel ----------------
// blocks 0..255  : 4 (b,n) rows each -> kmsg, pTE, pTF (transposed), qc
// blocks 256..267: W1bf (256x192, W1 cols 64..255)
// blocks 268..276: W2bf (144x256, rows reordered: edge(72..135)|logit(0..71)|pad)
__global__ __launch_bounds__(256) void semla_pre(
    const float* __restrict__ invs, const float* __restrict__ equis,
    const float* __restrict__ Wq, const float* __restrict__ bq,
    const float* __restrict__ Wk, const float* __restrict__ bk,
    const float* __restrict__ Wc, const float* __restrict__ Wi, const float* __restrict__ bi,
    const float* __restrict__ W1, const float* __restrict__ W2,
    __bf16* __restrict__ W1bf, __bf16* __restrict__ W2bf,
    float* __restrict__ qc, float* __restrict__ kmsg,
    float* __restrict__ pTE, float* __restrict__ pTF)
{
    const int blk = blockIdx.x, tid = threadIdx.x;
    if (blk < 256) {
        const int r0 = blk * 4;
        __shared__ __align__(16) float sInv4[4][256];
        __shared__ __align__(16) float sEqu4[4][192];
        __shared__ __align__(16) float sQm4[4][64];
        #pragma unroll
        for (int j = 0; j < 4; ++j) {
            sInv4[j][tid] = invs[(size_t)(r0 + j) * 256 + tid];
            if (tid < 192) sEqu4[j][tid] = equis[(size_t)(r0 + j) * 192 + tid];
        }
        __syncthreads();
        {   // projF = invs @ Wi.T + bi  -> pTF[b][f][n]
            float acc[4] = {0.f, 0.f, 0.f, 0.f};
            const float* w = &Wi[tid * 256];
            for (int i = 0; i < 256; i += 4) {
                f32x4_t ww = *(const f32x4_t*)&w[i];
                #pragma unroll
                for (int j = 0; j < 4; ++j) {
                    const float* x = &sInv4[j][i];
                    acc[j] += ww.x * x[0] + ww.y * x[1] + ww.z * x[2] + ww.w * x[3];
                }
            }
            const float bb = bi[tid];
            #pragma unroll
            for (int j = 0; j < 4; ++j) {
                const int bb_ = (r0 + j) >> 8, nl = (r0 + j) & 255;
                pTF[((size_t)bb_ * 256 + tid) * 256 + nl] = acc[j] + bb;
            }
        }
        if (tid < 128) {   // qmsg (to LDS) / kmsg (to global)
            const int d = tid & 63;
            const float* w = (tid < 64) ? &Wq[d * 256] : &Wk[d * 256];
            float acc[4] = {0.f, 0.f, 0.f, 0.f};
            for (int i = 0; i < 256; i += 4) {
                f32x4_t ww = *(const f32x4_t*)&w[i];
                #pragma unroll
                for (int j = 0; j < 4; ++j) {
                    const float* x = &sInv4[j][i];
                    acc[j] += ww.x * x[0] + ww.y * x[1] + ww.z * x[2] + ww.w * x[3];
                }
            }
            if (tid < 64) {
                const float bb = bq[d];
                #pragma unroll
                for (int j = 0; j < 4; ++j) sQm4[j][d] = acc[j] + bb;
            } else {
                const float bb = bk[d];
                #pragma unroll
                for (int j = 0; j < 4; ++j) kmsg[(size_t)(r0 + j) * 64 + d] = acc[j] + bb;
            }
        }
        if (tid < 192) {   // projE = equis @ Wc.T -> pTE[b][c][d][n]
            const int c = tid >> 6, e = tid & 63;
            const float* w = &Wc[e * 64];
            float acc[4] = {0.f, 0.f, 0.f, 0.f};
            for (int dd = 0; dd < 64; dd += 4) {
                f32x4_t ww = *(const f32x4_t*)&w[dd];
                #pragma unroll
                for (int j = 0; j < 4; ++j) {
                    const float* x = &sEqu4[j][c * 64 + dd];
                    acc[j] += ww.x * x[0] + ww.y * x[1] + ww.z * x[2] + ww.w * x[3];
                }
            }
            #pragma unroll
            for (int j = 0; j < 4; ++j) {
                const int bb_ = (r0 + j) >> 8, nl = (r0 + j) & 255;
                pTE[(((size_t)bb_ * 3 + c) * 64 + e) * 256 + nl] = acc[j];
            }
        }
        __syncthreads();   // sQm4 ready
        {   // qc[r][o] = sum_{d<64} W1[o][d] * qmsg[r][d]
            const float* w = &W1[tid * 256];
            float acc[4] = {0.f, 0.f, 0.f, 0.f};
            for (int d = 0; d < 64; d += 4) {
                f32x4_t ww = *(const f32x4_t*)&w[d];
                #pragma unroll
                for (int j = 0; j < 4; ++j) {
                    const float* x = &sQm4[j][d];
                    acc[j] += ww.x * x[0] + ww.y * x[1] + ww.z * x[2] + ww.w * x[3];
                }
            }
            #pragma unroll
            for (int j = 0; j < 4; ++j) qc[(size_t)(r0 + j) * 256 + tid] = acc[j];
        }
    } else if (blk < 268) {   // W1bf: 256x192, source col 64+k
        const int base = (blk - 256) * 4096;
        #pragma unroll
        for (int it = 0; it < 16; ++it) {
            const int e = base + it * 256 + tid;   // < 49152
            const int o = e / 192, k = e % 192;
            W1bf[e] = (__bf16)W1[o * 256 + 64 + k];
        }
    } else if (blk < 277) {   // W2bf reordered
        const int base = (blk - 268) * 4096;
        #pragma unroll
        for (int it = 0; it < 16; ++it) {
            const int e = base + it * 256 + tid;   // < 36864
            const int o = e >> 8, cc = e & 255;
            const int src = (o < 64) ? (72 + o) : (o < 136 ? o - 64 : -1);
            W2bf[e] = (src >= 0) ? (__bf16)W2[src * 256 + cc] : (__bf16)0.f;
        }
    }
}

// ---------------- main fused kernel: one 16-wave workgroup per (b,q) --------
__global__ __launch_bounds__(1024, 4) void semla_main(
    const float* __restrict__ equis, const float* __restrict__ edges,
    const int* __restrict__ adj,
    const __bf16* __restrict__ W1bf, const __bf16* __restrict__ W2bf,
    const float* __restrict__ qc, const float* __restrict__ kmsg,
    const float* __restrict__ pTE, const float* __restrict__ pTF,
    const float* __restrict__ b1, const float* __restrict__ b2,
    float* __restrict__ outE, float* __restrict__ outI, float* __restrict__ outEdge)
{
    const int bqid = ((blockIdx.x & 7) << 7) | (blockIdx.x >> 3);  // XCD swizzle
    const int b = bqid >> 8;
    const int tid = threadIdx.x;
    const int wave = tid >> 6, lane = tid & 63;
    const int arow = lane & 15, kgrp = lane >> 4;

    __shared__ __align__(16) __bf16 sX[KV * 192];   // 12KB X tile (K=192)
    __shared__ __align__(16) __bf16 sH[KV * 256];   // 16KB H tile
    __shared__ __align__(16) float  sS[KV * SP];    // p values
    __shared__ __align__(16) float  sB1[256];
    __shared__ __align__(16) float  sB2[144];
    __shared__ __align__(16) float  sEquiQ[192];
    __shared__ float sF[72], sL[72], sL2[72];
    __shared__ int   sAdj[2][KV];

    if (tid < 256) sB1[tid] = b1[tid] + qc[(size_t)bqid * 256 + tid];
    if (tid < 144) sB2[tid] = (tid < 64) ? b2[72 + tid] : (tid < 136 ? b2[tid - 64] : 0.f);
    if (tid < 192) sEquiQ[tid] = equis[(size_t)bqid * 192 + tid];

    // ---- loop-invariant weights in registers ----
    bf16x8_t w1r[6];                 // 16 FF cols per wave, K=192 (24 VGPR)
    #pragma unroll
    for (int ks = 0; ks < 6; ++ks)
        w1r[ks] = *(const bf16x8_t*)
            &W1bf[((wave << 4) + arow) * 192 + ks * 32 + (kgrp << 3)];
    const int w2row = (((wave <= 8) ? wave : 0) << 4) + arow;   // waves 0-8 real
    bf16x8_t w2r[8];                 // 16 out cols (32 VGPR)
    #pragma unroll
    for (int ks = 0; ks < 8; ++ks)
        w2r[ks] = *(const bf16x8_t*)&W2bf[(w2row << 8) + ks * 32 + (kgrp << 3)];

    // persistent per-thread state
    float m_run = -1e30f, l_run = 0.f, l2_run = 0.f;   // waves 4-8 (softmax owner)
    float accE = 0.f;                                   // tid<192: (c_e,d_e)
    float accI = 0.f;                                   // tid in [256,512): fidx
    const int c_e = tid >> 6, d_e = tid & 63;
    const int fidx = tid - 256, h_i = (tid - 256) >> 5;
    const bool isE = (tid < 192), isI = (tid >= 256 && tid < 512);
    const bool sm = (wave >= 4 && wave <= 8);
    const bool chOK = (wave < 8) || (arow < 8);        // wave 8: ch 64..71 only
    const int ch = ((wave - 4) << 4) + arow;           // softmax channel (waves 4-8)

    // staging roles
    const int rowK = tid >> 3,          c8K = (tid & 7) << 3;          // tid<256
    const int rowD = (tid - 256) >> 3,  c8D = ((tid - 256) & 7) << 3;  // tid 256-511
    const int rowE = (tid - 512) >> 4,  c4E = (((tid - 512) & 15) << 2) + 128; // tid>=512

    __syncthreads();                       // init LDS visible

    // ---- prologue: stage X[0] + sAdj[0] ----
    {
        if (tid < 256) {
            const float* p = &kmsg[(size_t)(b * 256 + rowK) * 64 + c8K];
            *(bf16x8_t*)&sX[swzX(rowK, c8K)] =
                cvt8(*(const f32x4_t*)p, *(const f32x4_t*)(p + 4));
        } else if (tid < 512) {
            const float* ek = &equis[(size_t)(b * 256 + rowD) * 192 + c8D];
            f32x4_t e0a = *(const f32x4_t*)(ek),       e0b = *(const f32x4_t*)(ek + 4);
            f32x4_t e1a = *(const f32x4_t*)(ek + 64),  e1b = *(const f32x4_t*)(ek + 68);
            f32x4_t e2a = *(const f32x4_t*)(ek + 128), e2b = *(const f32x4_t*)(ek + 132);
            f32x4_t q0a = *(const f32x4_t*)&sEquiQ[c8D],       q0b = *(const f32x4_t*)&sEquiQ[c8D + 4];
            f32x4_t q1a = *(const f32x4_t*)&sEquiQ[64 + c8D],  q1b = *(const f32x4_t*)&sEquiQ[68 + c8D];
            f32x4_t q2a = *(const f32x4_t*)&sEquiQ[128 + c8D], q2b = *(const f32x4_t*)&sEquiQ[132 + c8D];
            *(bf16x8_t*)&sX[swzX(rowD, 64 + c8D)] =
                cvt8(e0a * q0a + e1a * q1a + e2a * q2a,
                     e0b * q0b + e1b * q1b + e2b * q2b);
        } else {
            f32x4_t ed = *(const f32x4_t*)
                &edges[((size_t)bqid * 256 + rowE) * 64 + (c4E - 128)];
            *(bf16x4_t*)&sX[swzX(rowE, c4E)] = cvt4(ed);
        }
        if (tid < KV) sAdj[0][tid] = adj[(size_t)bqid * 256 + tid];
    }
    __syncthreads();                       // X[0] ready

    for (int kt = 0; kt < 8; ++kt) {
        const int k0 = kt * KV;
        const int cur = kt & 1;

        // ============ PHASE A: edges prefetch + passB(kt-1) + GEMM1 + silu ======
        f32x4_t edPf = {0.f, 0.f, 0.f, 0.f};
        if (kt < 7 && tid >= 512)
            edPf = *(const f32x4_t*)
                &edges[((size_t)bqid * 256 + k0 + KV + rowE) * 64 + (c4E - 128)];

        if (kt > 0) {
            const int k0P = k0 - KV;
            if (isE) {
                float a = accE * sF[d_e];
                const float* pe = &pTE[(((size_t)b * 3 + c_e) * 64 + d_e) * 256 + k0P];
                #pragma unroll
                for (int t = 0; t < 8; ++t) {
                    f32x4_t w = *(const f32x4_t*)&pe[t * 4];
                    a += sS[(4 * t + 0) * SP + d_e] * w.x;
                    a += sS[(4 * t + 1) * SP + d_e] * w.y;
                    a += sS[(4 * t + 2) * SP + d_e] * w.z;
                    a += sS[(4 * t + 3) * SP + d_e] * w.w;
                }
                accE = a;
            }
            if (isI) {
                float a = accI * sF[64 + h_i];
                const float* pf = &pTF[((size_t)b * 256 + fidx) * 256 + k0P];
                #pragma unroll
                for (int t = 0; t < 8; ++t) {
                    f32x4_t w = *(const f32x4_t*)&pf[t * 4];
                    a += sS[(4 * t + 0) * SP + 64 + h_i] * w.x;
                    a += sS[(4 * t + 1) * SP + 64 + h_i] * w.y;
                    a += sS[(4 * t + 2) * SP + 64 + h_i] * w.z;
                    a += sS[(4 * t + 3) * SP + 64 + h_i] * w.w;
                }
                accI = a;
            }
        }

        // GEMM1 (K=192, W1 in regs; 16 cols/wave) + silu -> sH
        f32x4_t acc1[2];
        {
            const f32x4_t z = {0.f, 0.f, 0.f, 0.f};
            acc1[0] = z; acc1[1] = z;
        }
        #pragma unroll
        for (int ks = 0; ks < 6; ++ks) {
            const int kk = ks * 32 + (kgrp << 3);
            bf16x8_t a0 = *(const bf16x8_t*)&sX[swzX(arow, kk)];
            bf16x8_t a1 = *(const bf16x8_t*)&sX[swzX(16 + arow, kk)];
            acc1[0] = __builtin_amdgcn_mfma_f32_16x16x32_bf16(a0, w1r[ks], acc1[0], 0, 0, 0);
            acc1[1] = __builtin_amdgcn_mfma_f32_16x16x32_bf16(a1, w1r[ks], acc1[1], 0, 0, 0);
        }
        {
            const int ccol = (wave << 4) + arow;
            const float bb = sB1[ccol];
            #pragma unroll
            for (int rt = 0; rt < 2; ++rt)
                #pragma unroll
                for (int j = 0; j < 4; ++j) {
                    const int row = (rt << 4) + (kgrp << 2) + j;
                    float x = acc1[rt][j] + bb;
                    sH[swzH(row, ccol)] = (__bf16)(x / (1.f + __expf(-x)));
                }
        }
        __syncthreads();                   // (1) H ready, passB done, sS free

        // ============ PHASE B: staged loads + GEMM2 + softmax + X[kt+1] =========
        f32x4_t kmA, kmB;                                   // tid<256
        f32x4_t e0a_, e0b_, e1a_, e1b_, e2a_, e2b_;         // tid 256-511
        int adjN = 0;
        if (kt < 7) {
            const int kbN = b * 256 + k0 + KV;
            if (tid < 256) {
                const float* p = &kmsg[(size_t)(kbN + rowK) * 64 + c8K];
                kmA = *(const f32x4_t*)p;
                kmB = *(const f32x4_t*)(p + 4);
            } else if (tid < 512) {
                const float* ek = &equis[(size_t)(kbN + rowD) * 192 + c8D];
                e0a_ = *(const f32x4_t*)(ek);       e0b_ = *(const f32x4_t*)(ek + 4);
                e1a_ = *(const f32x4_t*)(ek + 64);  e1b_ = *(const f32x4_t*)(ek + 68);
                e2a_ = *(const f32x4_t*)(ek + 128); e2b_ = *(const f32x4_t*)(ek + 132);
            }
            if (tid < KV) adjN = adj[(size_t)bqid * 256 + k0 + KV + tid];
        }

        // GEMM2 (waves 0-8; W2 in regs)
        if (wave <= 8) {
            f32x4_t acc2[2];
            {
                const f32x4_t z = {0.f, 0.f, 0.f, 0.f};
                acc2[0] = z; acc2[1] = z;
            }
            #pragma unroll
            for (int ks = 0; ks < 8; ++ks) {
                const int kk = ks * 32 + (kgrp << 3);
                bf16x8_t a0 = *(const bf16x8_t*)&sH[swzH(arow, kk)];
                bf16x8_t a1 = *(const bf16x8_t*)&sH[swzH(16 + arow, kk)];
                acc2[0] = __builtin_amdgcn_mfma_f32_16x16x32_bf16(a0, w2r[ks], acc2[0], 0, 0, 0);
                acc2[1] = __builtin_amdgcn_mfma_f32_16x16x32_bf16(a1, w2r[ks], acc2[1], 0, 0, 0);
            }
            if (wave < 4) {
                // edge channels: direct store
                const int col = (wave << 4) + arow;
                const float bb2 = sB2[col];
                #pragma unroll
                for (int rt = 0; rt < 2; ++rt)
                    #pragma unroll
                    for (int j = 0; j < 4; ++j) {
                        const int r = (rt << 4) + (kgrp << 2) + j;
                        outEdge[((size_t)bqid * 256 + k0 + r) * 64 + col] = acc2[rt][j] + bb2;
                    }
            } else {
                // logit channel ch: wave holds all 32 rows across kgrp lanes
                const float bb2 = sB2[(wave << 4) + arow];
                float s_[8];
                unsigned adm = 0;
                float xm = -1e30f;
                #pragma unroll
                for (int rt = 0; rt < 2; ++rt)
                    #pragma unroll
                    for (int j = 0; j < 4; ++j) {
                        const int r = (rt << 4) + (kgrp << 2) + j;
                        const float v = acc2[rt][j] + bb2;
                        s_[rt * 4 + j] = v;
                        if (sAdj[cur][r]) {
                            adm |= (1u << (rt * 4 + j));
                            xm = fmaxf(xm, v);
                        }
                    }
                xm = fmaxf(xm, __shfl_xor(xm, 16));
                xm = fmaxf(xm, __shfl_xor(xm, 32));
                const float mN = fmaxf(m_run, xm);
                const float f = __expf(m_run - mN);
                float s1 = 0.f, s2 = 0.f;
                #pragma unroll
                for (int rt = 0; rt < 2; ++rt)
                    #pragma unroll
                    for (int j = 0; j < 4; ++j) {
                        const int r = (rt << 4) + (kgrp << 2) + j;
                        const float p = ((adm >> (rt * 4 + j)) & 1u)
                                        ? __expf(s_[rt * 4 + j] - mN) : 0.f;
                        if (chOK) sS[r * SP + ch] = p;
                        s1 += p; s2 += p * p;
                    }
                s1 += __shfl_xor(s1, 16); s1 += __shfl_xor(s1, 32);
                s2 += __shfl_xor(s2, 16); s2 += __shfl_xor(s2, 32);
                l_run = l_run * f + s1;
                l2_run = l2_run * f * f + s2;
                m_run = mN;
                if (kgrp == 0 && chOK) sF[ch] = f;
            }
        }

        // write X[kt+1] from staged regs (sX free since barrier (1))
        if (kt < 7) {
            if (tid < 256) {
                *(bf16x8_t*)&sX[swzX(rowK, c8K)] = cvt8(kmA, kmB);
            } else if (tid < 512) {
                f32x4_t q0a = *(const f32x4_t*)&sEquiQ[c8D],       q0b = *(const f32x4_t*)&sEquiQ[c8D + 4];
                f32x4_t q1a = *(const f32x4_t*)&sEquiQ[64 + c8D],  q1b = *(const f32x4_t*)&sEquiQ[68 + c8D];
                f32x4_t q2a = *(const f32x4_t*)&sEquiQ[128 + c8D], q2b = *(const f32x4_t*)&sEquiQ[132 + c8D];
                *(bf16x8_t*)&sX[swzX(rowD, 64 + c8D)] =
                    cvt8(e0a_ * q0a + e1a_ * q1a + e2a_ * q2a,
                         e0b_ * q0b + e1b_ * q1b + e2b_ * q2b);
            } else {
                *(bf16x4_t*)&sX[swzX(rowE, c4E)] = cvt4(edPf);
            }
            if (tid < KV) sAdj[cur ^ 1][tid] = adjN;
        }
        __syncthreads();                   // (2) sS/sF + X[kt+1] ready
    }

    // ---- final passB (kt=7 tile) ----
    {
        const int k0P = 224;
        if (isE) {
            float a = accE * sF[d_e];
            const float* pe = &pTE[(((size_t)b * 3 + c_e) * 64 + d_e) * 256 + k0P];
            #pragma unroll
            for (int t = 0; t < 8; ++t) {
                f32x4_t w = *(const f32x4_t*)&pe[t * 4];
                a += sS[(4 * t + 0) * SP + d_e] * w.x;
                a += sS[(4 * t + 1) * SP + d_e] * w.y;
                a += sS[(4 * t + 2) * SP + d_e] * w.z;
                a += sS[(4 * t + 3) * SP + d_e] * w.w;
            }
            accE = a;
        }
        if (isI) {
            float a = accI * sF[64 + h_i];
            const float* pf = &pTF[((size_t)b * 256 + fidx) * 256 + k0P];
            #pragma unroll
            for (int t = 0; t < 8; ++t) {
                f32x4_t w = *(const f32x4_t*)&pf[t * 4];
                a += sS[(4 * t + 0) * SP + 64 + h_i] * w.x;
                a += sS[(4 * t + 1) * SP + 64 + h_i] * w.y;
                a += sS[(4 * t + 2) * SP + 64 + h_i] * w.z;
                a += sS[(4 * t + 3) * SP + 64 + h_i] * w.w;
            }
            accI = a;
        }
    }

    // ---- finalize: publish l, l2; write pre-GEMV outputs ----
    if (sm && kgrp == 0 && chOK) { sL[ch] = l_run; sL2[ch] = l2_run; }
    __syncthreads();
    if (isE) {
        const float ll = sL[d_e];
        outE[(size_t)bqid * 192 + tid] = accE * sqrtf(sL2[d_e]) / (ll * ll);
    }
    if (isI) {
        const float ll = sL[64 + h_i];
        outI[(size_t)bqid * 256 + fidx] = accI * sqrtf(sL2[64 + h_i]) / (ll * ll);
    }
}

// ---------------- post-kernel: final Wa / Wo GEMVs, in place ----------------
__global__ __launch_bounds__(256) void semla_post(
    const float* __restrict__ Wa, const float* __restrict__ Wo,
    const float* __restrict__ bo,
    float* __restrict__ outE, float* __restrict__ outI)
{
    __shared__ __align__(16) float hE[4][192];
    __shared__ __align__(16) float hI[4][256];
    const int blk = blockIdx.x, tid = threadIdx.x;
    const int r0 = blk * 4;
    #pragma unroll
    for (int r = 0; r < 4; ++r) {
        if (tid < 192) hE[r][tid] = outE[(size_t)(r0 + r) * 192 + tid];
        hI[r][tid] = outI[(size_t)(r0 + r) * 256 + tid];
    }
    __syncthreads();
    if (tid < 192) {                        // equi_updates = hE @ Wa^T
        const int c = tid >> 6, e = tid & 63;
        float wa[64];
        #pragma unroll
        for (int d = 0; d < 64; d += 4) {
            f32x4_t w = *(const f32x4_t*)&Wa[e * 64 + d];
            wa[d] = w.x; wa[d + 1] = w.y; wa[d + 2] = w.z; wa[d + 3] = w.w;
        }
        #pragma unroll
        for (int r = 0; r < 4; ++r) {
            float s = 0.f;
            #pragma unroll
            for (int d = 0; d < 64; ++d) s += hE[r][c * 64 + d] * wa[d];
            outE[((size_t)(r0 + r) * 3 + c) * 64 + e] = s;
        }
    }
    {                                       // inv_updates = hI @ Wo^T + bo
        const float bb = bo[tid];
        const float* wo = &Wo[tid * 256];
        #pragma unroll
        for (int r = 0; r < 4; ++r) {
            float s = 0.f;
            for (int i = 0; i < 256; i += 4) {
                f32x4_t w = *(const f32x4_t*)&wo[i];
                s += w.x * hI[r][i] + w.y * hI[r][i + 1]
                   + w.z * hI[r][i + 2] + w.w * hI[r][i + 3];
            }
            outI[(size_t)(r0 + r) * 256 + tid] = s + bb;
        }
    }
}

extern "C" void kernel_launch(void* const* d_in, const int* in_sizes, int n_in,
                              void* d_out, int out_size, void* d_ws, size_t ws_size,
                              hipStream_t stream) {
    (void)in_sizes; (void)n_in; (void)out_size; (void)ws_size;
    const float* equis = (const float*)d_in[0];
    const float* invs  = (const float*)d_in[1];
    const float* edges = (const float*)d_in[2];
    const int*   adj   = (const int*)d_in[3];
    const float* Wq = (const float*)d_in[4];
    const float* bq = (const float*)d_in[5];
    const float* Wk = (const float*)d_in[6];
    const float* bk = (const float*)d_in[7];
    const float* W1 = (const float*)d_in[8];
    const float* b1 = (const float*)d_in[9];
    const float* W2 = (const float*)d_in[10];
    const float* b2 = (const float*)d_in[11];
    const float* Wc = (const float*)d_in[12];
    const float* Wa = (const float*)d_in[13];
    const float* Wi = (const float*)d_in[14];
    const float* bi = (const float*)d_in[15];
    const float* Wo = (const float*)d_in[16];
    const float* bo = (const float*)d_in[17];

    float* out = (float*)d_out;
    float* outE    = out;                  // (B,N,3,64)  = 196608
    float* outI    = out + 196608;         // (B,N,256)   = 262144
    float* outEdge = out + 458752;         // (B,N,N,64)  = 16777216

    char* ws = (char*)d_ws;
    __bf16* W1bf = (__bf16*)(ws);                    //  98304 B (256x192)
    __bf16* W2bf = (__bf16*)(ws + 98304);            //  73728 B (144x256)
    float* qc    = (float*)(ws + 172032);            // 1048576 B
    float* kmsg  = (float*)(ws + 1220608);           //  262144 B
    float* pTE   = (float*)(ws + 1482752);           //  786432 B
    float* pTF   = (float*)(ws + 2269184);           // 1048576 B -> 3317760 total

    semla_pre<<<277, 256, 0, stream>>>(invs, equis, Wq, bq, Wk, bk, Wc, Wi, bi,
                                       W1, W2, W1bf, W2bf, qc, kmsg, pTE, pTF);
    semla_main<<<1024, 1024, 0, stream>>>(equis, edges, adj, W1bf, W2bf, qc, kmsg,
                                          pTE, pTF, b1, b2,
                                          outE, outI, outEdge);
    semla_post<<<256, 256, 0, stream>>>(Wa, Wo, bo, outE, outI);
}